// Round 1
// baseline (382.024 us; speedup 1.0000x reference)
//
#include <hip/hip_runtime.h>
#include <math.h>

// Problem constants (fixed by the reference's setup_inputs)
constexpr int B = 2, G = 8, D = 16, H = 256, W = 320;
constexpr int HW = H * W;
constexpr float EPS = 1e-5f;

__device__ __forceinline__ float sigmoidf_(float x) {
    return 1.0f / (1.0f + __expf(-x));
}

__device__ __forceinline__ int reflect_(int i, int n) {
    // jnp.pad 'reflect' (edge not repeated): -1 -> 1, n -> n-2
    return i < 0 ? -i : (i >= n ? 2 * n - 2 - i : i);
}

// ---------------------------------------------------------------------------
// Kernel 1: PixelwiseNet -> view_weight [B,HW]
// One thread per (b,h,w); loops over D. BN folded into weights (LDS).
// Uses sigmoid monotonicity: max_d sigmoid(h_d) = sigmoid(max_d h_d).
// ---------------------------------------------------------------------------
__global__ __launch_bounds__(256) void k_pixelwise(
    const float* __restrict__ x1,
    const float* __restrict__ w0, const float* __restrict__ g0, const float* __restrict__ b0,
    const float* __restrict__ w1, const float* __restrict__ g1, const float* __restrict__ b1,
    const float* __restrict__ w2, const float* __restrict__ bias2,
    float* __restrict__ vw_out)
{
    __shared__ float sW0[128], sB0[16], sW1[128], sB1[8], sW2[8], sBias2;
    const int tid = threadIdx.x;
    const float rs = rsqrtf(1.0f + EPS);
    if (tid < 128) {
        sW0[tid] = w0[tid] * g0[tid >> 3] * rs;
    } else {
        const int t = tid - 128;
        sW1[t] = w1[t] * g1[t >> 4] * rs;
    }
    if (tid < 16) sB0[tid] = b0[tid];
    if (tid >= 16 && tid < 24) sB1[tid - 16] = b1[tid - 16];
    if (tid >= 24 && tid < 32) sW2[tid - 24] = w2[tid - 24];
    if (tid == 32) sBias2 = bias2[0];
    __syncthreads();

    const int pid = blockIdx.x * 256 + tid;
    const int b = pid / HW;
    const int p = pid - b * HW;
    const float* xb = x1 + (size_t)b * G * D * HW + p;

    float hmax = -3.4e38f;
    for (int d = 0; d < D; ++d) {
        float x[G];
        #pragma unroll
        for (int g = 0; g < G; ++g) x[g] = xb[(size_t)(g * D + d) * HW];
        float l1[16];
        #pragma unroll
        for (int o = 0; o < 16; ++o) {
            float a = sB0[o];
            #pragma unroll
            for (int c = 0; c < 8; ++c) a = fmaf(sW0[o * 8 + c], x[c], a);
            l1[o] = fmaxf(a, 0.0f);
        }
        float l2[8];
        #pragma unroll
        for (int o = 0; o < 8; ++o) {
            float a = sB1[o];
            #pragma unroll
            for (int c = 0; c < 16; ++c) a = fmaf(sW1[o * 16 + c], l1[c], a);
            l2[o] = fmaxf(a, 0.0f);
        }
        float h3 = sBias2;
        #pragma unroll
        for (int c = 0; c < 8; ++c) h3 = fmaf(sW2[c], l2[c], h3);
        hmax = fmaxf(hmax, h3);
    }
    vw_out[pid] = sigmoidf_(hmax);
}

// ---------------------------------------------------------------------------
// Kernel 2: SimilarityNet on x1*view_weight -> s [B,D,HW]; also xn [B,D,HW].
// One thread per (b,d,h,w).
// ---------------------------------------------------------------------------
__global__ __launch_bounds__(256) void k_similarity(
    const float* __restrict__ x1,
    const float* __restrict__ depth_sample,
    const float* __restrict__ depth_min, const float* __restrict__ depth_max,
    const float* __restrict__ w0, const float* __restrict__ g0, const float* __restrict__ b0,
    const float* __restrict__ w1, const float* __restrict__ g1, const float* __restrict__ b1,
    const float* __restrict__ w2, const float* __restrict__ bias2,
    const float* __restrict__ vw_in,
    float* __restrict__ s_out, float* __restrict__ xn_out)
{
    __shared__ float sW0[128], sB0[16], sW1[128], sB1[8], sW2[8], sBias2;
    const int tid = threadIdx.x;
    const float rs = rsqrtf(1.0f + EPS);
    if (tid < 128) {
        sW0[tid] = w0[tid] * g0[tid >> 3] * rs;
    } else {
        const int t = tid - 128;
        sW1[t] = w1[t] * g1[t >> 4] * rs;
    }
    if (tid < 16) sB0[tid] = b0[tid];
    if (tid >= 16 && tid < 24) sB1[tid - 16] = b1[tid - 16];
    if (tid >= 24 && tid < 32) sW2[tid - 24] = w2[tid - 24];
    if (tid == 32) sBias2 = bias2[0];
    __syncthreads();

    const int pid = blockIdx.x * 256 + tid;       // over B*D*HW
    const int b = pid / (D * HW);
    const int r = pid - b * D * HW;
    const int d = r / HW;
    const int p = r - d * HW;

    const float vw = vw_in[b * HW + p];
    const float* xb = x1 + ((size_t)(b * G * D + d)) * HW + p;  // + g*D*HW per channel

    float x[G];
    #pragma unroll
    for (int g = 0; g < G; ++g) x[g] = xb[(size_t)g * D * HW] * vw;

    float l1[16];
    #pragma unroll
    for (int o = 0; o < 16; ++o) {
        float a = sB0[o];
        #pragma unroll
        for (int c = 0; c < 8; ++c) a = fmaf(sW0[o * 8 + c], x[c], a);
        l1[o] = fmaxf(a, 0.0f);
    }
    float l2[8];
    #pragma unroll
    for (int o = 0; o < 8; ++o) {
        float a = sB1[o];
        #pragma unroll
        for (int c = 0; c < 16; ++c) a = fmaf(sW1[o * 16 + c], l1[c], a);
        l2[o] = fmaxf(a, 0.0f);
    }
    float h3 = sBias2;
    #pragma unroll
    for (int c = 0; c < 8; ++c) h3 = fmaf(sW2[c], l2[c], h3);

    s_out[pid] = h3;

    // normalized inverse depth
    const float inv_min = 1.0f / depth_min[b];
    const float inv_max = 1.0f / depth_max[b];
    const float ds = depth_sample[pid];
    xn_out[pid] = (1.0f / ds - inv_max) / (inv_min - inv_max);
}

// ---------------------------------------------------------------------------
// Kernel 3: neighbor gathers on s and xn, dw, score, softmax over D, depth.
// One thread per (b,h,w).
// ---------------------------------------------------------------------------
__global__ __launch_bounds__(256) void k_score_depth(
    const float* __restrict__ s_arr, const float* __restrict__ xn,
    const float* __restrict__ offset, const float* __restrict__ depth_sample,
    float* __restrict__ out)
{
    const int pid = blockIdx.x * 256 + threadIdx.x;   // over B*HW
    const int b = pid / HW;
    const int p = pid - b * HW;
    const int h = p / W;
    const int w = p - h * W;

    // per-pixel neighbor weights: o2 = offset[:, s] (dilation 2 of base grid,
    // i.e. X2/scale-2 taps), o1 = offset[:, s+9] (X1/scale-1 taps)
    float o1[9], o2[9];
    const float* ob = offset + (size_t)b * 18 * HW + p;
    #pragma unroll
    for (int s = 0; s < 9; ++s) {
        o2[s] = ob[(size_t)s * HW];
        o1[s] = ob[(size_t)(s + 9) * HW];
    }

    // reflected row/col offsets for the two dilations
    int ry1[3], ry2[3], cx1[3], cx2[3];
    #pragma unroll
    for (int i = 0; i < 3; ++i) {
        ry1[i] = reflect_(h + (i - 1) * 2, H) * W;
        ry2[i] = reflect_(h + (i - 1) * 4, H) * W;
        cx1[i] = reflect_(w + (i - 1) * 2, W);
        cx2[i] = reflect_(w + (i - 1) * 4, W);
    }

    const float* sb = s_arr + (size_t)b * D * HW;
    const float* xb = xn + (size_t)b * D * HW;

    float score[D];
    for (int d = 0; d < D; ++d) {
        const float* sd = sb + (size_t)d * HW;
        const float* xd = xb + (size_t)d * HW;
        float accs = 0.0f, accx = 0.0f;
        #pragma unroll
        for (int s = 0; s < 9; ++s) {
            const int sy = s / 3, sx = s % 3;
            const int a1 = ry1[sy] + cx1[sx];
            const int a2 = ry2[sy] + cx2[sx];
            accs += 0.5f * (o1[s] * sd[a1] + o2[s] * sd[a2]);
            accx += 0.5f * (o1[s] * xd[a1] + o2[s] * xd[a2]);
        }
        const float xc = xd[p];
        float diff = fminf(fabsf(accx - xc) * 40.0f, 4.0f);   // /0.025, clip hi 4 (lo 0 automatic)
        const float dwv = sigmoidf_((2.0f - diff) * 2.0f);
        score[d] = accs * dwv;
    }

    float m = score[0];
    #pragma unroll
    for (int d = 1; d < D; ++d) m = fmaxf(m, score[d]);

    float sum = 0.0f, acc = 0.0f;
    const float* dsb = depth_sample + (size_t)b * D * HW + p;
    #pragma unroll
    for (int d = 0; d < D; ++d) {
        const float e = __expf(score[d] - m);
        sum += e;
        acc = fmaf(dsb[(size_t)d * HW], e, acc);
    }
    out[pid] = acc / sum;
}

// ---------------------------------------------------------------------------
extern "C" void kernel_launch(void* const* d_in, const int* in_sizes, int n_in,
                              void* d_out, int out_size, void* d_ws, size_t ws_size,
                              hipStream_t stream)
{
    const float* x1           = (const float*)d_in[0];
    const float* offset       = (const float*)d_in[1];
    const float* depth_sample = (const float*)d_in[2];
    const float* depth_min    = (const float*)d_in[3];
    const float* depth_max    = (const float*)d_in[4];
    const float* s_w0 = (const float*)d_in[5];
    const float* s_g0 = (const float*)d_in[6];
    const float* s_b0 = (const float*)d_in[7];
    const float* s_w1 = (const float*)d_in[8];
    const float* s_g1 = (const float*)d_in[9];
    const float* s_b1 = (const float*)d_in[10];
    const float* s_w2 = (const float*)d_in[11];
    const float* s_bias2 = (const float*)d_in[12];
    const float* p_w0 = (const float*)d_in[13];
    const float* p_g0 = (const float*)d_in[14];
    const float* p_b0 = (const float*)d_in[15];
    const float* p_w1 = (const float*)d_in[16];
    const float* p_g1 = (const float*)d_in[17];
    const float* p_b1 = (const float*)d_in[18];
    const float* p_w2 = (const float*)d_in[19];
    const float* p_bias2 = (const float*)d_in[20];

    float* vw    = (float*)d_ws;             // B*HW
    float* s_arr = vw + (size_t)B * HW;      // B*D*HW
    float* xn    = s_arr + (size_t)B * D * HW;

    k_pixelwise<<<(B * HW) / 256, 256, 0, stream>>>(
        x1, p_w0, p_g0, p_b0, p_w1, p_g1, p_b1, p_w2, p_bias2, vw);

    k_similarity<<<(B * D * HW) / 256, 256, 0, stream>>>(
        x1, depth_sample, depth_min, depth_max,
        s_w0, s_g0, s_b0, s_w1, s_g1, s_b1, s_w2, s_bias2,
        vw, s_arr, xn);

    k_score_depth<<<(B * HW) / 256, 256, 0, stream>>>(
        s_arr, xn, offset, depth_sample, (float*)d_out);
}

// Round 2
// 142.823 us; speedup vs baseline: 2.6748x; 2.6748x over previous
//
#include <hip/hip_runtime.h>
#include <math.h>

// Problem constants (fixed by the reference's setup_inputs)
constexpr int B = 2, G = 8, D = 16, H = 256, W = 320;
constexpr int HW = H * W;
constexpr float EPS = 1e-5f;

__device__ __forceinline__ float sigmoidf_(float x) {
    return 1.0f / (1.0f + __expf(-x));
}

__device__ __forceinline__ int reflect_(int i, int n) {
    // jnp.pad 'reflect' (edge not repeated): -1 -> 1, n -> n-2
    return i < 0 ? -i : (i >= n ? 2 * n - 2 - i : i);
}

// ---------------------------------------------------------------------------
// Fused kernel: PixelwiseNet + max-over-D + SimilarityNet, ONE read of x1.
// Block = 256 threads = 16 pixels x 16 depths. Thread (pi, dt) loads its 8
// group values of x1, runs the pixelwise MLP head, max-reduces over dt via
// LDS to get view_weight, then reuses the same x registers (scaled by vw)
// for the SimilarityNet MLP. Writes s [B,D,HW] and xn [B,D,HW].
// ---------------------------------------------------------------------------
__global__ __launch_bounds__(256) void k_fused(
    const float* __restrict__ x1,
    const float* __restrict__ depth_sample,
    const float* __restrict__ depth_min, const float* __restrict__ depth_max,
    const float* __restrict__ sw0, const float* __restrict__ sg0, const float* __restrict__ sb0,
    const float* __restrict__ sw1, const float* __restrict__ sg1, const float* __restrict__ sb1,
    const float* __restrict__ sw2, const float* __restrict__ sbias2,
    const float* __restrict__ pw0, const float* __restrict__ pg0, const float* __restrict__ pb0,
    const float* __restrict__ pw1, const float* __restrict__ pg1, const float* __restrict__ pb1,
    const float* __restrict__ pw2, const float* __restrict__ pbias2,
    float* __restrict__ s_out, float* __restrict__ xn_out)
{
    __shared__ float sPW0[128], sPB0[16], sPW1[128], sPB1[8], sPW2[8];
    __shared__ float sSW0[128], sSB0[16], sSW1[128], sSB1[8], sSW2[8];
    __shared__ float sPBias2, sSBias2;
    __shared__ float h_lds[256];

    const int tid = threadIdx.x;
    const float rs = rsqrtf(1.0f + EPS);
    if (tid < 128) {
        sPW0[tid] = pw0[tid] * pg0[tid >> 3] * rs;
        sSW0[tid] = sw0[tid] * sg0[tid >> 3] * rs;
        sPW1[tid] = pw1[tid] * pg1[tid >> 4] * rs;
        sSW1[tid] = sw1[tid] * sg1[tid >> 4] * rs;
    } else if (tid < 144) {
        sPB0[tid - 128] = pb0[tid - 128];
    } else if (tid < 160) {
        sSB0[tid - 144] = sb0[tid - 144];
    } else if (tid < 168) {
        sPB1[tid - 160] = pb1[tid - 160];
    } else if (tid < 176) {
        sSB1[tid - 168] = sb1[tid - 168];
    } else if (tid < 184) {
        sPW2[tid - 176] = pw2[tid - 176];
    } else if (tid < 192) {
        sSW2[tid - 184] = sw2[tid - 184];
    } else if (tid == 192) {
        sPBias2 = pbias2[0];
    } else if (tid == 193) {
        sSBias2 = sbias2[0];
    }
    __syncthreads();

    const int pi = tid & 15;          // pixel within block
    const int dt = tid >> 4;          // depth hypothesis index
    const int pid = blockIdx.x * 16 + pi;   // global pixel over B*HW
    const int b = pid / HW;
    const int p = pid - b * HW;

    // ---- load this thread's 8 group values: x1[b, g, dt, p] ----
    const float* xb = x1 + ((size_t)(b * G * D) + dt) * HW + p;
    float x[G];
    #pragma unroll
    for (int g = 0; g < G; ++g) x[g] = xb[(size_t)g * D * HW];

    // ---- PixelwiseNet MLP head (no sigmoid yet; monotone) ----
    {
        float l1[16];
        #pragma unroll
        for (int o = 0; o < 16; ++o) {
            float a = sPB0[o];
            #pragma unroll
            for (int c = 0; c < 8; ++c) a = fmaf(sPW0[o * 8 + c], x[c], a);
            l1[o] = fmaxf(a, 0.0f);
        }
        float l2[8];
        #pragma unroll
        for (int o = 0; o < 8; ++o) {
            float a = sPB1[o];
            #pragma unroll
            for (int c = 0; c < 16; ++c) a = fmaf(sPW1[o * 16 + c], l1[c], a);
            l2[o] = fmaxf(a, 0.0f);
        }
        float h3 = sPBias2;
        #pragma unroll
        for (int c = 0; c < 8; ++c) h3 = fmaf(sPW2[c], l2[c], h3);
        h_lds[tid] = h3;
    }
    __syncthreads();

    // ---- max over the 16 depth hypotheses for this pixel ----
    float hmax = -3.4e38f;
    #pragma unroll
    for (int k = 0; k < 16; ++k) hmax = fmaxf(hmax, h_lds[k * 16 + pi]);
    const float vw = sigmoidf_(hmax);

    // ---- SimilarityNet on x * vw (reuse registers) ----
    #pragma unroll
    for (int g = 0; g < G; ++g) x[g] *= vw;

    float l1[16];
    #pragma unroll
    for (int o = 0; o < 16; ++o) {
        float a = sSB0[o];
        #pragma unroll
        for (int c = 0; c < 8; ++c) a = fmaf(sSW0[o * 8 + c], x[c], a);
        l1[o] = fmaxf(a, 0.0f);
    }
    float l2[8];
    #pragma unroll
    for (int o = 0; o < 8; ++o) {
        float a = sSB1[o];
        #pragma unroll
        for (int c = 0; c < 16; ++c) a = fmaf(sSW1[o * 16 + c], l1[c], a);
        l2[o] = fmaxf(a, 0.0f);
    }
    float h3 = sSBias2;
    #pragma unroll
    for (int c = 0; c < 8; ++c) h3 = fmaf(sSW2[c], l2[c], h3);

    const size_t oidx = (size_t)(b * D + dt) * HW + p;
    s_out[oidx] = h3;

    // ---- normalized inverse depth ----
    const float inv_min = 1.0f / depth_min[b];
    const float inv_max = 1.0f / depth_max[b];
    const float ds = depth_sample[oidx];
    xn_out[oidx] = (1.0f / ds - inv_max) / (inv_min - inv_max);
}

// ---------------------------------------------------------------------------
// Kernel 3: neighbor gathers on s and xn, dw, score, softmax over D, depth.
// One thread per (b,h,w).
// ---------------------------------------------------------------------------
__global__ __launch_bounds__(256) void k_score_depth(
    const float* __restrict__ s_arr, const float* __restrict__ xn,
    const float* __restrict__ offset, const float* __restrict__ depth_sample,
    float* __restrict__ out)
{
    const int pid = blockIdx.x * 256 + threadIdx.x;   // over B*HW
    const int b = pid / HW;
    const int p = pid - b * HW;
    const int h = p / W;
    const int w = p - h * W;

    // per-pixel neighbor weights: offset[:, s] pairs with the dilation-4
    // (X2) taps, offset[:, s+9] with the dilation-2 (X1) taps
    float o1[9], o2[9];
    const float* ob = offset + (size_t)b * 18 * HW + p;
    #pragma unroll
    for (int s = 0; s < 9; ++s) {
        o2[s] = ob[(size_t)s * HW];
        o1[s] = ob[(size_t)(s + 9) * HW];
    }

    // reflected row/col offsets for the two dilations
    int ry1[3], ry2[3], cx1[3], cx2[3];
    #pragma unroll
    for (int i = 0; i < 3; ++i) {
        ry1[i] = reflect_(h + (i - 1) * 2, H) * W;
        ry2[i] = reflect_(h + (i - 1) * 4, H) * W;
        cx1[i] = reflect_(w + (i - 1) * 2, W);
        cx2[i] = reflect_(w + (i - 1) * 4, W);
    }

    const float* sb = s_arr + (size_t)b * D * HW;
    const float* xb = xn + (size_t)b * D * HW;

    float score[D];
    for (int d = 0; d < D; ++d) {
        const float* sd = sb + (size_t)d * HW;
        const float* xd = xb + (size_t)d * HW;
        float accs = 0.0f, accx = 0.0f;
        #pragma unroll
        for (int s = 0; s < 9; ++s) {
            const int sy = s / 3, sx = s % 3;
            const int a1 = ry1[sy] + cx1[sx];
            const int a2 = ry2[sy] + cx2[sx];
            accs += 0.5f * (o1[s] * sd[a1] + o2[s] * sd[a2]);
            accx += 0.5f * (o1[s] * xd[a1] + o2[s] * xd[a2]);
        }
        const float xc = xd[p];
        float diff = fminf(fabsf(accx - xc) * 40.0f, 4.0f);   // /0.025, clip hi 4
        const float dwv = sigmoidf_((2.0f - diff) * 2.0f);
        score[d] = accs * dwv;
    }

    float m = score[0];
    #pragma unroll
    for (int d = 1; d < D; ++d) m = fmaxf(m, score[d]);

    float sum = 0.0f, acc = 0.0f;
    const float* dsb = depth_sample + (size_t)b * D * HW + p;
    #pragma unroll
    for (int d = 0; d < D; ++d) {
        const float e = __expf(score[d] - m);
        sum += e;
        acc = fmaf(dsb[(size_t)d * HW], e, acc);
    }
    out[pid] = acc / sum;
}

// ---------------------------------------------------------------------------
extern "C" void kernel_launch(void* const* d_in, const int* in_sizes, int n_in,
                              void* d_out, int out_size, void* d_ws, size_t ws_size,
                              hipStream_t stream)
{
    const float* x1           = (const float*)d_in[0];
    const float* offset       = (const float*)d_in[1];
    const float* depth_sample = (const float*)d_in[2];
    const float* depth_min    = (const float*)d_in[3];
    const float* depth_max    = (const float*)d_in[4];
    const float* s_w0 = (const float*)d_in[5];
    const float* s_g0 = (const float*)d_in[6];
    const float* s_b0 = (const float*)d_in[7];
    const float* s_w1 = (const float*)d_in[8];
    const float* s_g1 = (const float*)d_in[9];
    const float* s_b1 = (const float*)d_in[10];
    const float* s_w2 = (const float*)d_in[11];
    const float* s_bias2 = (const float*)d_in[12];
    const float* p_w0 = (const float*)d_in[13];
    const float* p_g0 = (const float*)d_in[14];
    const float* p_b0 = (const float*)d_in[15];
    const float* p_w1 = (const float*)d_in[16];
    const float* p_g1 = (const float*)d_in[17];
    const float* p_b1 = (const float*)d_in[18];
    const float* p_w2 = (const float*)d_in[19];
    const float* p_bias2 = (const float*)d_in[20];

    float* s_arr = (float*)d_ws;             // B*D*HW
    float* xn    = s_arr + (size_t)B * D * HW;

    k_fused<<<(B * HW) / 16, 256, 0, stream>>>(
        x1, depth_sample, depth_min, depth_max,
        s_w0, s_g0, s_b0, s_w1, s_g1, s_b1, s_w2, s_bias2,
        p_w0, p_g0, p_b0, p_w1, p_g1, p_b1, p_w2, p_bias2,
        s_arr, xn);

    k_score_depth<<<(B * HW) / 256, 256, 0, stream>>>(
        s_arr, xn, offset, depth_sample, (float*)d_out);
}